// Round 7
// baseline (982.429 us; speedup 1.0000x reference)
//
#include <hip/hip_runtime.h>
#include <hip/hip_bf16.h>

#define BATCH 256
#define TSTEPS 1024
#define NIN 128
#define NL 64
#define NH 128
#define NOUT 32

typedef __attribute__((ext_vector_type(8))) short short8;
typedef __attribute__((ext_vector_type(4))) float f32x4;

__device__ inline int pk2(float x, float y) {
    __hip_bfloat162 h = __float22bfloat162_rn(make_float2(x, y));
    union { __hip_bfloat162 h; int i; } u;
    u.h = h;
    return u.i;
}
__device__ inline short bf1(float x) {
    __hip_bfloat16 h = __float2bfloat16(x);
    union { __hip_bfloat16 h; short s; } u;
    u.h = h;
    return u.s;
}

#define WG_BARRIER()  asm volatile("s_waitcnt lgkmcnt(0)\n\ts_barrier" ::: "memory")
#define WAVE_FENCE()  asm volatile("s_waitcnt lgkmcnt(0)" ::: "memory")

// ---------------------------------------------------------------------------
// Pass 1: u'[g][b][t][e] = bf16( C[l,:]·s[b,t,:] + h1[l] ),  l = g*4+e.
// MFMA GEMM, zero LDS, zero lgkm drains: C-frags stored DIRECTLY to global
// in g-major layout (4 contiguous 128B runs per store instr). Scan-side this
// layout is an 8B/step linear stream per lane (8 steps per 64B line -> L1).
// Grid: 512 WGs x 256 thr; wave: 8 iters x 16 rows.
// ---------------------------------------------------------------------------
__launch_bounds__(256, 1)
__global__ void ugemm_mfma(const float* __restrict__ input,
                           const float* __restrict__ C,
                           const float* __restrict__ h1,
                           unsigned short* __restrict__ u16) {
    const int lane = threadIdx.x & 63;
    const int wv   = threadIdx.x >> 6;
    const int c = lane & 15;
    const int q = lane >> 4;
    const long wbase = ((long)blockIdx.x * 4 + wv) * 128;  // first row (b*1024+t)

    // static A-frags: cA[mt][kf] = C[(mt*16+c), kf*32+q*8 .. +7] bf16
    short8 cA[4][4];
    #pragma unroll
    for (int mt = 0; mt < 4; ++mt)
        #pragma unroll
        for (int kf = 0; kf < 4; ++kf) {
            const float* p = C + (mt * 16 + c) * NIN + kf * 32 + q * 8;
            float4 r0 = *(const float4*)p;
            float4 r1 = *(const float4*)(p + 4);
            union { short8 s; int i[4]; } f;
            f.i[0] = pk2(r0.x, r0.y); f.i[1] = pk2(r0.z, r0.w);
            f.i[2] = pk2(r1.x, r1.y); f.i[3] = pk2(r1.z, r1.w);
            cA[mt][kf] = f.s;
        }
    f32x4 h1f[4];
    #pragma unroll
    for (int mt = 0; mt < 4; ++mt)
        h1f[mt] = *(const f32x4*)(h1 + mt * 16 + q * 4);

    float4 raw[8], rawn[8];
    {
        const float* sr = input + (wbase + c) * NIN;
        #pragma unroll
        for (int kf = 0; kf < 4; ++kf) {
            raw[2*kf]   = *(const float4*)(sr + kf * 32 + q * 8);
            raw[2*kf+1] = *(const float4*)(sr + kf * 32 + q * 8 + 4);
        }
    }

    for (int it = 0; it < 8; ++it) {
        if (it < 7) {
            const float* sr = input + (wbase + (it + 1) * 16 + c) * NIN;
            #pragma unroll
            for (int kf = 0; kf < 4; ++kf) {
                rawn[2*kf]   = *(const float4*)(sr + kf * 32 + q * 8);
                rawn[2*kf+1] = *(const float4*)(sr + kf * 32 + q * 8 + 4);
            }
        }
        short8 bf[4];
        #pragma unroll
        for (int kf = 0; kf < 4; ++kf) {
            union { short8 s; int i[4]; } f;
            f.i[0] = pk2(raw[2*kf].x,   raw[2*kf].y);
            f.i[1] = pk2(raw[2*kf].z,   raw[2*kf].w);
            f.i[2] = pk2(raw[2*kf+1].x, raw[2*kf+1].y);
            f.i[3] = pk2(raw[2*kf+1].z, raw[2*kf+1].w);
            bf[kf] = f.s;
        }
        long row = wbase + it * 16 + c;       // this lane's (b,t) row
        int b = (int)(row >> 10), t = (int)(row & 1023);
        #pragma unroll
        for (int mt = 0; mt < 4; ++mt) {
            f32x4 acc = __builtin_amdgcn_mfma_f32_16x16x32_bf16(cA[mt][0], bf[0], h1f[mt], 0, 0, 0);
            acc = __builtin_amdgcn_mfma_f32_16x16x32_bf16(cA[mt][1], bf[1], acc, 0, 0, 0);
            acc = __builtin_amdgcn_mfma_f32_16x16x32_bf16(cA[mt][2], bf[2], acc, 0, 0, 0);
            acc = __builtin_amdgcn_mfma_f32_16x16x32_bf16(cA[mt][3], bf[3], acc, 0, 0, 0);
            // direct store: g = mt*4+q, addr = ((g*256+b)*1024+t)*4 shorts
            size_t goff = (((size_t)(mt * 4 + q) * 256 + b) * 1024 + t) * 4;
            *(int2*)(u16 + goff) = make_int2(pk2(acc[0], acc[1]), pk2(acc[2], acc[3]));
        }
        #pragma unroll
        for (int j = 0; j < 8; ++j) raw[j] = rawn[j];
    }
}

// ---------------------------------------------------------------------------
// Pass 2: MFMA scan, ONE barrier per step. Grid 16 WGs x 256 thr.
// - H computed REDUNDANTLY per wave (full 128, 16 MFMAs) -> H hand-off is a
//   wave-local LDS round trip (lgkmcnt only, no barrier).
// - Z' M-split (wave w owns latents [16w,16w+16)) -> z exchange is the single
//   cross-wave barrier, double-buffered (zb0/zb1) for WAR safety.
// - MFMA2 K-split into two 2-chains + add (shorter dependent chain).
// ---------------------------------------------------------------------------
__launch_bounds__(256, 1)
__global__ void plrnn_scan_mfma(const float* __restrict__ A,
                                const float* __restrict__ W1,
                                const float* __restrict__ W2,
                                const float* __restrict__ h2,
                                const unsigned short* __restrict__ u16,
                                const float* __restrict__ Wout,
                                const float* __restrict__ bout,
                                float* __restrict__ out) {
    __shared__ __attribute__((aligned(16))) int zb0[8 * 16 * 4];    // 2 KB
    __shared__ __attribute__((aligned(16))) int zb1[8 * 16 * 4];    // 2 KB
    __shared__ __attribute__((aligned(16))) int hbuf[4][16 * 16 * 4]; // 4x4 KB

    const int lane = threadIdx.x & 63;
    const int w    = threadIdx.x >> 6;     // wave 0..3
    const int c = lane & 15;               // batch col
    const int q = lane >> 4;               // quad
    const int bbase = blockIdx.x * 16;
    int* hb = hbuf[w];

    // ---- static weight fragments ----
    short8 aw2[8][2];   // FULL W2: 8 H-tiles x K=64 (2 frags)
    #pragma unroll
    for (int mt = 0; mt < 8; ++mt)
        #pragma unroll
        for (int kt = 0; kt < 2; ++kt) {
            const float* p = W2 + (mt * 16 + c) * NL + kt * 32 + q * 8;
            short8 f;
            #pragma unroll
            for (int j = 0; j < 8; ++j) f[j] = bf1(p[j]);
            aw2[mt][kt] = f;
        }
    short8 aw1[4];      // own Z tile (w): K=128 (4 frags)
    #pragma unroll
    for (int kt = 0; kt < 4; ++kt) {
        const float* p = W1 + (w * 16 + c) * NH + kt * 32 + q * 8;
        short8 f;
        #pragma unroll
        for (int j = 0; j < 8; ++j) f[j] = bf1(p[j]);
        aw1[kt] = f;
    }
    f32x4 h2f[8];
    #pragma unroll
    for (int mt = 0; mt < 8; ++mt)
        h2f[mt] = *(const f32x4*)(h2 + mt * 16 + q * 4);
    const f32x4 af = *(const f32x4*)(A + w * 16 + q * 4);

    f32x4 zf = {0.f, 0.f, 0.f, 0.f};

    // LDS offsets (dwords)
    const int zw  = ((w * 2 + (q >> 1)) * 16 + c) * 4 + (q & 1) * 2;  // z write
    const int zr0 = (q * 16 + c) * 4;                                 // bz0
    const int zr1 = ((q + 4) * 16 + c) * 4;                           // bz1
    const int hw  = ((q >> 1) * 16 + c) * 4 + (q & 1) * 2;            // + mt*128
    const int hr0 = ((0 * 4 + q) * 16 + c) * 4;
    const int hr1 = ((1 * 4 + q) * 16 + c) * 4;
    const int hr2 = ((2 * 4 + q) * 16 + c) * 4;
    const int hr3 = ((3 * 4 + q) * 16 + c) * 4;

    // u stream: g = w*4+q, batch bbase+c; 8B per step, linear in t
    const unsigned short* ub =
        u16 + ((size_t)(w * 4 + q) * 256 + bbase + c) * 4096;
    int2 ucur = *(const int2*)ub;
    int2 unx  = *(const int2*)(ub + 4);

    // init zb0 = 0 (waves cover all blocks/dwords)
    *(int2*)&zb0[zw] = make_int2(0, 0);
    WG_BARRIER();

#define SCAN_STEP(SRC, DST, T)                                                  \
    {                                                                           \
        short8 bz0 = *(short8*)&SRC[zr0];                                       \
        short8 bz1 = *(short8*)&SRC[zr1];                                       \
        int tp = ((T) + 2 < TSTEPS) ? (T) + 2 : TSTEPS - 1;                     \
        int2 upf = *(const int2*)(ub + (size_t)tp * 4);                         \
        _Pragma("unroll")                                                       \
        for (int mt = 0; mt < 8; ++mt) {                                        \
            f32x4 acc = __builtin_amdgcn_mfma_f32_16x16x32_bf16(                \
                aw2[mt][0], bz0, h2f[mt], 0, 0, 0);                             \
            acc = __builtin_amdgcn_mfma_f32_16x16x32_bf16(                      \
                aw2[mt][1], bz1, acc, 0, 0, 0);                                 \
            *(int2*)&hb[hw + mt * 128] =                                        \
                make_int2(pk2(fmaxf(acc[0], 0.f), fmaxf(acc[1], 0.f)),          \
                          pk2(fmaxf(acc[2], 0.f), fmaxf(acc[3], 0.f)));         \
        }                                                                       \
        WAVE_FENCE();                                                           \
        short8 bh0 = *(short8*)&hb[hr0];                                        \
        short8 bh1 = *(short8*)&hb[hr1];                                        \
        short8 bh2 = *(short8*)&hb[hr2];                                        \
        short8 bh3 = *(short8*)&hb[hr3];                                        \
        f32x4 cin, zro = {0.f, 0.f, 0.f, 0.f};                                  \
        cin[0] = fmaf(zf[0], af[0], __int_as_float(ucur.x << 16));              \
        cin[1] = fmaf(zf[1], af[1], __int_as_float(ucur.x & 0xffff0000));       \
        cin[2] = fmaf(zf[2], af[2], __int_as_float(ucur.y << 16));              \
        cin[3] = fmaf(zf[3], af[3], __int_as_float(ucur.y & 0xffff0000));       \
        f32x4 aA = __builtin_amdgcn_mfma_f32_16x16x32_bf16(aw1[0], bh0, cin, 0, 0, 0); \
        aA = __builtin_amdgcn_mfma_f32_16x16x32_bf16(aw1[1], bh1, aA, 0, 0, 0); \
        f32x4 aB = __builtin_amdgcn_mfma_f32_16x16x32_bf16(aw1[2], bh2, zro, 0, 0, 0); \
        aB = __builtin_amdgcn_mfma_f32_16x16x32_bf16(aw1[3], bh3, aB, 0, 0, 0); \
        _Pragma("unroll")                                                       \
        for (int e = 0; e < 4; ++e)                                             \
            zf[e] = fminf(fmaxf(aA[e] + aB[e], -5.f), 5.f);                     \
        *(int2*)&DST[zw] = make_int2(pk2(zf[0], zf[1]), pk2(zf[2], zf[3]));     \
        ucur = unx; unx = upf;                                                  \
        WG_BARRIER();                                                           \
    }

    for (int t = 0; t < TSTEPS; t += 2) {
        SCAN_STEP(zb0, zb1, t);
        SCAN_STEP(zb1, zb0, t + 1);
    }
#undef SCAN_STEP

    // ---- epilogue: out = Wout @ Z + bout (final z in zb0; waves 0,1) ----
    if (w < 2) {
        short8 fz0 = *(short8*)&zb0[zr0];
        short8 fz1 = *(short8*)&zb0[zr1];
        const float* p0 = Wout + (w * 16 + c) * NL + q * 8;
        const float* p1 = p0 + 32;
        short8 fa, fb;
        #pragma unroll
        for (int j = 0; j < 8; ++j) { fa[j] = bf1(p0[j]); fb[j] = bf1(p1[j]); }
        f32x4 cb = *(const f32x4*)(bout + w * 16 + q * 4);
        f32x4 acc = __builtin_amdgcn_mfma_f32_16x16x32_bf16(fa, fz0, cb, 0, 0, 0);
        acc = __builtin_amdgcn_mfma_f32_16x16x32_bf16(fb, fz1, acc, 0, 0, 0);
        *(f32x4*)&out[(bbase + c) * 32 + w * 16 + q * 4] = acc;
    }
}

extern "C" void kernel_launch(void* const* d_in, const int* in_sizes, int n_in,
                              void* d_out, int out_size, void* d_ws, size_t ws_size,
                              hipStream_t stream) {
    const float* input = (const float*)d_in[0];
    const float* A     = (const float*)d_in[1];
    const float* W1    = (const float*)d_in[2];
    const float* W2    = (const float*)d_in[3];
    const float* h1    = (const float*)d_in[4];
    const float* h2    = (const float*)d_in[5];
    const float* C     = (const float*)d_in[6];
    const float* Wout  = (const float*)d_in[7];
    const float* bout  = (const float*)d_in[8];
    float* out = (float*)d_out;

    unsigned short* u16 = (unsigned short*)d_ws;   // 256*1024*64 bf16 = 33.5 MB

    ugemm_mfma<<<dim3(512), dim3(256), 0, stream>>>(input, C, h1, u16);
    plrnn_scan_mfma<<<dim3(16), dim3(256), 0, stream>>>(
        A, W1, W2, h2, u16, Wout, bout, out);
}